// Round 1
// baseline (1559.829 us; speedup 1.0000x reference)
//
#include <hip/hip_runtime.h>

#define D_IN 256
#define D_OUT 128
#define NEG_SLOPE 0.2

// ---------------------------------------------------------------------------
// Kernel 1: m = x @ W   (M x 256) @ (256 x 128) fp32, tiled 64x128, BK=32
// ---------------------------------------------------------------------------
__global__ __launch_bounds__(256) void gemm_xw(const float* __restrict__ x,
                                               const float* __restrict__ W,
                                               float* __restrict__ m, int M) {
    __shared__ float xs[64][33];     // +1 pad
    __shared__ float wsh[32][128];
    const int tid  = threadIdx.x;
    const int row0 = blockIdx.x * 64;
    const int tc   = tid & 15;       // col group: cols tc*8 .. tc*8+7
    const int tr   = tid >> 4;       // row group: rows tr*4 .. tr*4+3

    float acc[4][8];
#pragma unroll
    for (int i = 0; i < 4; ++i)
#pragma unroll
        for (int j = 0; j < 8; ++j) acc[i][j] = 0.f;

    for (int k0 = 0; k0 < D_IN; k0 += 32) {
        // stage x tile: 64 rows x 32 cols -> 512 float4s, 2 per thread
#pragma unroll
        for (int p = 0; p < 2; ++p) {
            int f = tid + p * 256;        // 0..511
            int r = f >> 3;               // 0..63
            int c = (f & 7) << 2;         // 0..28
            float4 v = make_float4(0.f, 0.f, 0.f, 0.f);
            if (row0 + r < M)
                v = *(const float4*)(x + (size_t)(row0 + r) * D_IN + k0 + c);
            *(float4*)(&xs[r][c]) = v;
        }
        // stage W tile: 32 rows x 128 cols -> 1024 float4s, 4 per thread
#pragma unroll
        for (int p = 0; p < 4; ++p) {
            int f = tid + p * 256;        // 0..1023
            int r = f >> 5;               // 0..31
            int c = (f & 31) << 2;        // 0..124
            *(float4*)(&wsh[r][c]) = *(const float4*)(W + (size_t)(k0 + r) * D_OUT + c);
        }
        __syncthreads();
#pragma unroll
        for (int kk = 0; kk < 32; ++kk) {
            float av[4], bv[8];
#pragma unroll
            for (int i = 0; i < 4; ++i) av[i] = xs[tr * 4 + i][kk];
#pragma unroll
            for (int j = 0; j < 8; ++j) bv[j] = wsh[kk][tc * 8 + j];
#pragma unroll
            for (int i = 0; i < 4; ++i)
#pragma unroll
                for (int j = 0; j < 8; ++j) acc[i][j] = fmaf(av[i], bv[j], acc[i][j]);
        }
        __syncthreads();
    }
#pragma unroll
    for (int i = 0; i < 4; ++i) {
        int r = row0 + tr * 4 + i;
        if (r < M) {
            *(float4*)(m + (size_t)r * D_OUT + tc * 8 + 0) = *(float4*)(&acc[i][0]);
            *(float4*)(m + (size_t)r * D_OUT + tc * 8 + 4) = *(float4*)(&acc[i][4]);
        }
    }
}

// ---------------------------------------------------------------------------
// Kernel 2: s[i] = m[i,:] . a_src,  d[i] = m[i,:] . a_dst   (fp64 accumulate)
// one wave per row; lane holds 2 consecutive dims (float2)
// ---------------------------------------------------------------------------
__global__ __launch_bounds__(256) void sd_kernel(const float* __restrict__ m,
                                                 const float* __restrict__ a,
                                                 double* __restrict__ s,
                                                 double* __restrict__ d, int M) {
    int wave = (int)((blockIdx.x * blockDim.x + threadIdx.x) >> 6);
    int lane = threadIdx.x & 63;
    if (wave >= M) return;
    float2 mv = ((const float2*)(m + (size_t)wave * D_OUT))[lane];
    float2 as = ((const float2*)a)[lane];            // a[0:128]  = a_src
    float2 ad = ((const float2*)(a + D_OUT))[lane];  // a[128:256]= a_dst
    double ps = (double)mv.x * as.x + (double)mv.y * as.y;
    double pd = (double)mv.x * ad.x + (double)mv.y * ad.y;
#pragma unroll
    for (int off = 32; off > 0; off >>= 1) {
        ps += __shfl_down(ps, off);
        pd += __shfl_down(pd, off);
    }
    if (lane == 0) { s[wave] = ps; d[wave] = pd; }
}

// ---------------------------------------------------------------------------
// Kernel 3: e = leaky_relu(s[src]+d[dst]); row_sum[src] += e   (fp64)
// ---------------------------------------------------------------------------
__global__ __launch_bounds__(256) void edge_e_kernel(const int* __restrict__ src,
                                                     const int* __restrict__ dst,
                                                     const double* __restrict__ s,
                                                     const double* __restrict__ d,
                                                     double* __restrict__ e,
                                                     double* __restrict__ row_sum,
                                                     int E) {
    int i = blockIdx.x * blockDim.x + threadIdx.x;
    if (i >= E) return;
    double v = s[src[i]] + d[dst[i]];
    v = (v > 0.0) ? v : v * NEG_SLOPE;
    e[i] = v;
    unsafeAtomicAdd(&row_sum[src[i]], v);   // hw global_atomic_add_f64
}

// ---------------------------------------------------------------------------
// Kernel 4: out[src] += (n_vals * e / row_sum[src]) * m[dst]
// one wave per edge (grid-stride); lane covers 2 dims, fp32 atomics
// ---------------------------------------------------------------------------
__global__ __launch_bounds__(256) void edge_scatter(const int* __restrict__ src,
                                                    const int* __restrict__ dst,
                                                    const float* __restrict__ nvals,
                                                    const double* __restrict__ e,
                                                    const double* __restrict__ row_sum,
                                                    const float* __restrict__ m,
                                                    float* __restrict__ out, int E) {
    int gwave  = (int)((blockIdx.x * blockDim.x + threadIdx.x) >> 6);
    int lane   = threadIdx.x & 63;
    int nwaves = (int)((gridDim.x * blockDim.x) >> 6);
    for (int i = gwave; i < E; i += nwaves) {
        int  si = src[i], di = dst[i];
        double cd = (double)nvals[i] * e[i] / row_sum[si];
        float  c  = (float)cd;
        float2 mv = ((const float2*)(m + (size_t)di * D_OUT))[lane];
        float* o  = out + (size_t)si * D_OUT + lane * 2;
        unsafeAtomicAdd(o + 0, mv.x * c);
        unsafeAtomicAdd(o + 1, mv.y * c);
    }
}

// ---------------------------------------------------------------------------
extern "C" void kernel_launch(void* const* d_in, const int* in_sizes, int n_in,
                              void* d_out, int out_size, void* d_ws, size_t ws_size,
                              hipStream_t stream) {
    const float* x     = (const float*)d_in[0];
    const float* W     = (const float*)d_in[1];
    const float* a     = (const float*)d_in[2];
    const float* nvals = (const float*)d_in[3];
    const int*   nsrc  = (const int*)d_in[4];
    const int*   ndst  = (const int*)d_in[5];
    const int M = in_sizes[0] / D_IN;   // 50000
    const int E = in_sizes[4];          // 1600000
    float* out = (float*)d_out;

    // workspace layout (all 16B-aligned)
    char* ws = (char*)d_ws;
    float*  m       = (float*)ws;                        // M*128 fp32   = 25.6 MB
    size_t off = (size_t)M * D_OUT * sizeof(float);
    double* e       = (double*)(ws + off); off += (size_t)E * sizeof(double);  // 12.8 MB
    double* svec    = (double*)(ws + off); off += (size_t)M * sizeof(double);
    double* dvec    = (double*)(ws + off); off += (size_t)M * sizeof(double);
    double* row_sum = (double*)(ws + off); off += (size_t)M * sizeof(double);

    // zero-init accumulators (ws/out are poisoned 0xAA before each timed call)
    hipMemsetAsync(out, 0, (size_t)out_size * sizeof(float), stream);
    hipMemsetAsync(row_sum, 0, (size_t)M * sizeof(double), stream);

    // 1) m = x @ W
    gemm_xw<<<(M + 63) / 64, 256, 0, stream>>>(x, W, m, M);

    // 2) s, d per row
    sd_kernel<<<(M * 64 + 255) / 256, 256, 0, stream>>>(m, a, svec, dvec, M);

    // 3) e + row_sum
    edge_e_kernel<<<(E + 255) / 256, 256, 0, stream>>>(nsrc, ndst, svec, dvec, e, row_sum, E);

    // 4) scatter
    edge_scatter<<<8192, 256, 0, stream>>>(nsrc, ndst, nvals, e, row_sum, m, out, E);
}

// Round 2
// 565.514 us; speedup vs baseline: 2.7582x; 2.7582x over previous
//
#include <hip/hip_runtime.h>

#define D_IN 256
#define D_OUT 128
#define NEG_SLOPE 0.2

// ---------------------------------------------------------------------------
// Kernel 1: m = x @ W   (M x 256) @ (256 x 128) fp32, tiled 64x128, BK=32
// ---------------------------------------------------------------------------
__global__ __launch_bounds__(256) void gemm_xw(const float* __restrict__ x,
                                               const float* __restrict__ W,
                                               float* __restrict__ m, int M) {
    __shared__ float xs[64][33];     // +1 pad
    __shared__ float wsh[32][128];
    const int tid  = threadIdx.x;
    const int row0 = blockIdx.x * 64;
    const int tc   = tid & 15;       // col group: cols tc*8 .. tc*8+7
    const int tr   = tid >> 4;       // row group: rows tr*4 .. tr*4+3

    float acc[4][8];
#pragma unroll
    for (int i = 0; i < 4; ++i)
#pragma unroll
        for (int j = 0; j < 8; ++j) acc[i][j] = 0.f;

    for (int k0 = 0; k0 < D_IN; k0 += 32) {
#pragma unroll
        for (int p = 0; p < 2; ++p) {
            int f = tid + p * 256;
            int r = f >> 3;
            int c = (f & 7) << 2;
            float4 v = make_float4(0.f, 0.f, 0.f, 0.f);
            if (row0 + r < M)
                v = *(const float4*)(x + (size_t)(row0 + r) * D_IN + k0 + c);
            *(float4*)(&xs[r][c]) = v;
        }
#pragma unroll
        for (int p = 0; p < 4; ++p) {
            int f = tid + p * 256;
            int r = f >> 5;
            int c = (f & 31) << 2;
            *(float4*)(&wsh[r][c]) = *(const float4*)(W + (size_t)(k0 + r) * D_OUT + c);
        }
        __syncthreads();
#pragma unroll
        for (int kk = 0; kk < 32; ++kk) {
            float av[4], bv[8];
#pragma unroll
            for (int i = 0; i < 4; ++i) av[i] = xs[tr * 4 + i][kk];
#pragma unroll
            for (int j = 0; j < 8; ++j) bv[j] = wsh[kk][tc * 8 + j];
#pragma unroll
            for (int i = 0; i < 4; ++i)
#pragma unroll
                for (int j = 0; j < 8; ++j) acc[i][j] = fmaf(av[i], bv[j], acc[i][j]);
        }
        __syncthreads();
    }
#pragma unroll
    for (int i = 0; i < 4; ++i) {
        int r = row0 + tr * 4 + i;
        if (r < M) {
            *(float4*)(m + (size_t)r * D_OUT + tc * 8 + 0) = *(float4*)(&acc[i][0]);
            *(float4*)(m + (size_t)r * D_OUT + tc * 8 + 4) = *(float4*)(&acc[i][4]);
        }
    }
}

// ---------------------------------------------------------------------------
// Kernel 2: s[i] = m[i,:] . a_src,  d[i] = m[i,:] . a_dst   (fp64 accumulate)
// ---------------------------------------------------------------------------
__global__ __launch_bounds__(256) void sd_kernel(const float* __restrict__ m,
                                                 const float* __restrict__ a,
                                                 double* __restrict__ s,
                                                 double* __restrict__ d, int M) {
    int wave = (int)((blockIdx.x * blockDim.x + threadIdx.x) >> 6);
    int lane = threadIdx.x & 63;
    if (wave >= M) return;
    float2 mv = ((const float2*)(m + (size_t)wave * D_OUT))[lane];
    float2 as = ((const float2*)a)[lane];
    float2 ad = ((const float2*)(a + D_OUT))[lane];
    double ps = (double)mv.x * as.x + (double)mv.y * as.y;
    double pd = (double)mv.x * ad.x + (double)mv.y * ad.y;
#pragma unroll
    for (int off = 32; off > 0; off >>= 1) {
        ps += __shfl_down(ps, off);
        pd += __shfl_down(pd, off);
    }
    if (lane == 0) { s[wave] = ps; d[wave] = pd; }
}

// ---------------------------------------------------------------------------
// CSR build: histogram -> single-block scan -> fill
// ---------------------------------------------------------------------------
__global__ __launch_bounds__(256) void count_kernel(const int* __restrict__ src,
                                                    int* __restrict__ counts, int E) {
    int i = blockIdx.x * blockDim.x + threadIdx.x;
    if (i < E) atomicAdd(&counts[src[i]], 1);
}

__global__ __launch_bounds__(1024) void scan_kernel(const int* __restrict__ counts,
                                                    int* __restrict__ rowptr,
                                                    int* __restrict__ cursor, int M) {
    __shared__ int part[1024];
    int t = threadIdx.x;
    int chunk = (M + 1023) / 1024;
    int b = t * chunk;
    int e = min(b + chunk, M);
    int s = 0;
    for (int i = b; i < e; ++i) s += counts[i];
    part[t] = s;
    __syncthreads();
    for (int off = 1; off < 1024; off <<= 1) {
        int v = (t >= off) ? part[t - off] : 0;
        __syncthreads();
        part[t] += v;
        __syncthreads();
    }
    int running = (t == 0) ? 0 : part[t - 1];
    for (int i = b; i < e; ++i) {
        rowptr[i] = running;
        cursor[i] = running;
        running += counts[i];
    }
    if (t == 1023) rowptr[M] = part[1023];
}

__global__ __launch_bounds__(256) void fill_kernel(const int* __restrict__ src,
                                                   const int* __restrict__ dst,
                                                   const float* __restrict__ nvals,
                                                   int* __restrict__ cursor,
                                                   int* __restrict__ dst_s,
                                                   float* __restrict__ nv_s, int E) {
    int i = blockIdx.x * blockDim.x + threadIdx.x;
    if (i >= E) return;
    int p = atomicAdd(&cursor[src[i]], 1);
    dst_s[p] = dst[i];
    nv_s[p]  = nvals[i];
}

// ---------------------------------------------------------------------------
// Kernel 5: one wave per output row. Pass A: local fp64 row_sum.
// Pass B: gather m[dst] rows, accumulate out row in registers. No atomics.
// ---------------------------------------------------------------------------
__global__ __launch_bounds__(256) void row_kernel(const int* __restrict__ rowptr,
                                                  const int* __restrict__ dst_s,
                                                  const float* __restrict__ nv_s,
                                                  const double* __restrict__ svec,
                                                  const double* __restrict__ dvec,
                                                  const float* __restrict__ m,
                                                  float* __restrict__ out, int M) {
    int r    = blockIdx.x * 4 + (threadIdx.x >> 6);
    int lane = threadIdx.x & 63;
    if (r >= M) return;
    int beg = rowptr[r], end = rowptr[r + 1];
    double sr = svec[r];

    // Pass A: row_sum (lane-parallel over edges, fp64 butterfly reduce)
    double sum = 0.0;
    for (int j = beg + lane; j < end; j += 64) {
        double v = sr + dvec[dst_s[j]];
        sum += (v > 0.0) ? v : v * NEG_SLOPE;
    }
#pragma unroll
    for (int off = 32; off > 0; off >>= 1) sum += __shfl_xor(sum, off);
    double inv = 1.0 / sum;

    // Pass B: accumulate
    float2 acc = make_float2(0.f, 0.f);
    int j = beg;
    for (; j + 4 <= end; j += 4) {
        int d0 = dst_s[j + 0], d1 = dst_s[j + 1], d2 = dst_s[j + 2], d3 = dst_s[j + 3];
        float2 m0 = ((const float2*)(m + (size_t)d0 * D_OUT))[lane];
        float2 m1 = ((const float2*)(m + (size_t)d1 * D_OUT))[lane];
        float2 m2 = ((const float2*)(m + (size_t)d2 * D_OUT))[lane];
        float2 m3 = ((const float2*)(m + (size_t)d3 * D_OUT))[lane];
        double v0 = sr + dvec[d0]; v0 = (v0 > 0.0) ? v0 : v0 * NEG_SLOPE;
        double v1 = sr + dvec[d1]; v1 = (v1 > 0.0) ? v1 : v1 * NEG_SLOPE;
        double v2 = sr + dvec[d2]; v2 = (v2 > 0.0) ? v2 : v2 * NEG_SLOPE;
        double v3 = sr + dvec[d3]; v3 = (v3 > 0.0) ? v3 : v3 * NEG_SLOPE;
        float c0 = (float)((double)nv_s[j + 0] * v0 * inv);
        float c1 = (float)((double)nv_s[j + 1] * v1 * inv);
        float c2 = (float)((double)nv_s[j + 2] * v2 * inv);
        float c3 = (float)((double)nv_s[j + 3] * v3 * inv);
        acc.x = fmaf(c0, m0.x, acc.x); acc.y = fmaf(c0, m0.y, acc.y);
        acc.x = fmaf(c1, m1.x, acc.x); acc.y = fmaf(c1, m1.y, acc.y);
        acc.x = fmaf(c2, m2.x, acc.x); acc.y = fmaf(c2, m2.y, acc.y);
        acc.x = fmaf(c3, m3.x, acc.x); acc.y = fmaf(c3, m3.y, acc.y);
    }
    for (; j < end; ++j) {
        int dj = dst_s[j];
        float2 mv = ((const float2*)(m + (size_t)dj * D_OUT))[lane];
        double v = sr + dvec[dj]; v = (v > 0.0) ? v : v * NEG_SLOPE;
        float c = (float)((double)nv_s[j] * v * inv);
        acc.x = fmaf(c, mv.x, acc.x); acc.y = fmaf(c, mv.y, acc.y);
    }
    ((float2*)(out + (size_t)r * D_OUT))[lane] = acc;
}

// ---------------------------------------------------------------------------
extern "C" void kernel_launch(void* const* d_in, const int* in_sizes, int n_in,
                              void* d_out, int out_size, void* d_ws, size_t ws_size,
                              hipStream_t stream) {
    const float* x     = (const float*)d_in[0];
    const float* W     = (const float*)d_in[1];
    const float* a     = (const float*)d_in[2];
    const float* nvals = (const float*)d_in[3];
    const int*   nsrc  = (const int*)d_in[4];
    const int*   ndst  = (const int*)d_in[5];
    const int M = in_sizes[0] / D_IN;   // 50000
    const int E = in_sizes[4];          // 1600000
    float* out = (float*)d_out;

    // workspace layout (16B-aligned chunks)
    char* ws = (char*)d_ws;
    size_t off = 0;
    float*  m       = (float*)(ws + off);  off += (size_t)M * D_OUT * sizeof(float); // 25.6 MB
    double* svec    = (double*)(ws + off); off += (size_t)M * sizeof(double);
    double* dvec    = (double*)(ws + off); off += (size_t)M * sizeof(double);
    int*    counts  = (int*)(ws + off);    off += ((size_t)M * sizeof(int) + 15) & ~15ull;
    int*    rowptr  = (int*)(ws + off);    off += ((size_t)(M + 1) * sizeof(int) + 15) & ~15ull;
    int*    cursor  = (int*)(ws + off);    off += ((size_t)M * sizeof(int) + 15) & ~15ull;
    int*    dst_s   = (int*)(ws + off);    off += (size_t)E * sizeof(int);           // 6.4 MB
    float*  nv_s    = (float*)(ws + off);  off += (size_t)E * sizeof(float);         // 6.4 MB

    hipMemsetAsync(counts, 0, (size_t)M * sizeof(int), stream);

    // 1) m = x @ W
    gemm_xw<<<(M + 63) / 64, 256, 0, stream>>>(x, W, m, M);
    // 2) s, d per row (fp64)
    sd_kernel<<<(M * 64 + 255) / 256, 256, 0, stream>>>(m, a, svec, dvec, M);
    // 3) CSR build
    count_kernel<<<(E + 255) / 256, 256, 0, stream>>>(nsrc, counts, E);
    scan_kernel<<<1, 1024, 0, stream>>>(counts, rowptr, cursor, M);
    fill_kernel<<<(E + 255) / 256, 256, 0, stream>>>(nsrc, ndst, nvals, cursor, dst_s, nv_s, E);
    // 4) gather + accumulate per row (no atomics)
    row_kernel<<<(M + 3) / 4, 256, 0, stream>>>(rowptr, dst_s, nv_s, svec, dvec, m, out, M);
}

// Round 3
// 546.197 us; speedup vs baseline: 2.8558x; 1.0354x over previous
//
#include <hip/hip_runtime.h>

#define D_IN 256
#define D_OUT 128
#define NEG_SLOPE 0.2
#define CAP 128   // per-row LDS coefficient cache

// ---------------------------------------------------------------------------
// Dispatch 1: fused  [blocks 0..gemmBlocks)  : m = x @ W  (128x128 tile, 8x8/thr)
//                    [blocks gemmBlocks.. )  : counts histogram of src
// ---------------------------------------------------------------------------
__global__ __launch_bounds__(256) void gemm_count(
    const float* __restrict__ x, const float* __restrict__ W,
    float* __restrict__ m, int M,
    const int* __restrict__ src, int* __restrict__ counts, int E,
    int gemmBlocks) {
    __shared__ float xs[32][132];   // [k][row], pad 132: b128 reads 2-way max
    __shared__ float wsh[32][132];  // [k][col], pad for staging-write conflicts

    if ((int)blockIdx.x >= gemmBlocks) {
        int bid  = blockIdx.x - gemmBlocks;
        int base = (bid * 256 + (int)threadIdx.x) * 4;
        if (base + 4 <= E) {
            int4 s4 = *(const int4*)(src + base);
            atomicAdd(&counts[s4.x], 1); atomicAdd(&counts[s4.y], 1);
            atomicAdd(&counts[s4.z], 1); atomicAdd(&counts[s4.w], 1);
        } else {
            for (int i = base; i < E; ++i) atomicAdd(&counts[src[i]], 1);
        }
        return;
    }

    const int tid  = threadIdx.x;
    const int row0 = blockIdx.x * 128;
    const int ty   = tid >> 4;    // 0..15 -> rows ty*8..ty*8+7
    const int tx   = tid & 15;    // 0..15 -> cols tx*4..+3 and 64+tx*4..+3

    float acc[8][8];
#pragma unroll
    for (int i = 0; i < 8; ++i)
#pragma unroll
        for (int j = 0; j < 8; ++j) acc[i][j] = 0.f;

    for (int k0 = 0; k0 < D_IN; k0 += 32) {
        // stage x tile transposed: 128 rows x 32 k -> xs[k][row]
#pragma unroll
        for (int p = 0; p < 4; ++p) {
            int f  = tid + p * 256;        // 0..1023
            int rr = f >> 3;               // 0..127
            int cc = (f & 7) << 2;         // 0..28
            float4 v = make_float4(0.f, 0.f, 0.f, 0.f);
            if (row0 + rr < M)
                v = *(const float4*)(x + (size_t)(row0 + rr) * D_IN + k0 + cc);
            xs[cc + 0][rr] = v.x; xs[cc + 1][rr] = v.y;
            xs[cc + 2][rr] = v.z; xs[cc + 3][rr] = v.w;
        }
        // stage W tile: 32 k x 128 cols
#pragma unroll
        for (int p = 0; p < 4; ++p) {
            int f  = tid + p * 256;        // 0..1023
            int rr = f >> 5;               // 0..31
            int cc = (f & 31) << 2;        // 0..124
            *(float4*)(&wsh[rr][cc]) = *(const float4*)(W + (size_t)(k0 + rr) * D_OUT + cc);
        }
        __syncthreads();
#pragma unroll 4
        for (int kk = 0; kk < 32; ++kk) {
            float4 a0 = *(const float4*)(&xs[kk][ty * 8]);
            float4 a1 = *(const float4*)(&xs[kk][ty * 8 + 4]);
            float4 b0 = *(const float4*)(&wsh[kk][tx * 4]);
            float4 b1 = *(const float4*)(&wsh[kk][64 + tx * 4]);
            float av[8] = {a0.x, a0.y, a0.z, a0.w, a1.x, a1.y, a1.z, a1.w};
            float bv[8] = {b0.x, b0.y, b0.z, b0.w, b1.x, b1.y, b1.z, b1.w};
#pragma unroll
            for (int i = 0; i < 8; ++i)
#pragma unroll
                for (int j = 0; j < 8; ++j)
                    acc[i][j] = fmaf(av[i], bv[j], acc[i][j]);
        }
        __syncthreads();
    }
#pragma unroll
    for (int i = 0; i < 8; ++i) {
        int rr = row0 + ty * 8 + i;
        if (rr < M) {
            *(float4*)(m + (size_t)rr * D_OUT + tx * 4) =
                make_float4(acc[i][0], acc[i][1], acc[i][2], acc[i][3]);
            *(float4*)(m + (size_t)rr * D_OUT + 64 + tx * 4) =
                make_float4(acc[i][4], acc[i][5], acc[i][6], acc[i][7]);
        }
    }
}

// ---------------------------------------------------------------------------
// Dispatch 2: fused  block 0: exclusive scan counts -> rowptr, cursor
//                    blocks 1.. : s/d = m . a_src / a_dst  (fp64, 1 wave/row)
// ---------------------------------------------------------------------------
__global__ __launch_bounds__(256) void scan_sd(
    const int* __restrict__ counts, int* __restrict__ rowptr, int* __restrict__ cursor,
    const float* __restrict__ m, const float* __restrict__ a,
    double* __restrict__ svec, double* __restrict__ dvec, int M) {
    __shared__ int part[256];
    if (blockIdx.x == 0) {
        int t = threadIdx.x;
        int chunk = (M + 255) >> 8;
        int b = t * chunk, e = min(b + chunk, M);
        int s = 0;
        for (int i = b; i < e; ++i) s += counts[i];
        part[t] = s;
        __syncthreads();
        for (int off = 1; off < 256; off <<= 1) {
            int v = (t >= off) ? part[t - off] : 0;
            __syncthreads();
            part[t] += v;
            __syncthreads();
        }
        int running = (t == 0) ? 0 : part[t - 1];
        for (int i = b; i < e; ++i) {
            rowptr[i] = running; cursor[i] = running; running += counts[i];
        }
        if (t == 255) rowptr[M] = part[255];
        return;
    }
    int r    = (blockIdx.x - 1) * 4 + (threadIdx.x >> 6);
    int lane = threadIdx.x & 63;
    if (r >= M) return;
    float2 mv = ((const float2*)(m + (size_t)r * D_OUT))[lane];
    float2 as = ((const float2*)a)[lane];
    float2 ad = ((const float2*)(a + D_OUT))[lane];
    double ps = (double)mv.x * as.x + (double)mv.y * as.y;
    double pd = (double)mv.x * ad.x + (double)mv.y * ad.y;
#pragma unroll
    for (int off = 32; off > 0; off >>= 1) {
        ps += __shfl_down(ps, off);
        pd += __shfl_down(pd, off);
    }
    if (lane == 0) { svec[r] = ps; dvec[r] = pd; }
}

// ---------------------------------------------------------------------------
// Dispatch 3: fill CSR, packed {dst, nv} int2, one 8B scattered store/edge
// ---------------------------------------------------------------------------
__global__ __launch_bounds__(256) void fill_kernel(
    const int* __restrict__ src, const int* __restrict__ dst,
    const float* __restrict__ nvals, int* __restrict__ cursor,
    int2* __restrict__ edges, int E) {
    int base = (blockIdx.x * 256 + (int)threadIdx.x) * 4;
    if (base + 4 <= E) {
        int4   s4 = *(const int4*)(src + base);
        int4   d4 = *(const int4*)(dst + base);
        float4 n4 = *(const float4*)(nvals + base);
        int p;
        p = atomicAdd(&cursor[s4.x], 1); edges[p] = make_int2(d4.x, __float_as_int(n4.x));
        p = atomicAdd(&cursor[s4.y], 1); edges[p] = make_int2(d4.y, __float_as_int(n4.y));
        p = atomicAdd(&cursor[s4.z], 1); edges[p] = make_int2(d4.z, __float_as_int(n4.z));
        p = atomicAdd(&cursor[s4.w], 1); edges[p] = make_int2(d4.w, __float_as_int(n4.w));
    } else {
        for (int i = base; i < E; ++i) {
            int p = atomicAdd(&cursor[src[i]], 1);
            edges[p] = make_int2(dst[i], __float_as_int(nvals[i]));
        }
    }
}

// ---------------------------------------------------------------------------
// Dispatch 4: one wave per row. Pass A: fp64 row_sum + cache {dst, nv*v} in LDS.
// Pass B: pure float gather-accumulate, unroll 8 for MLP. No atomics.
// ---------------------------------------------------------------------------
__global__ __launch_bounds__(256) void row_kernel(
    const int* __restrict__ rowptr, const int2* __restrict__ edges,
    const double* __restrict__ svec, const double* __restrict__ dvec,
    const float* __restrict__ m, float* __restrict__ out, int M) {
    __shared__ int   s_dst[4][CAP];
    __shared__ float s_c[4][CAP];
    int w    = threadIdx.x >> 6;
    int lane = threadIdx.x & 63;
    int r    = blockIdx.x * 4 + w;
    if (r >= M) return;
    int beg = rowptr[r], end = rowptr[r + 1], len = end - beg;
    double sr  = svec[r];
    double sum = 0.0;
    for (int j = lane; j < len; j += 64) {
        int2 ed = edges[beg + j];
        double v = sr + dvec[ed.x];
        v = (v > 0.0) ? v : v * NEG_SLOPE;
        sum += v;
        if (j < CAP) {
            s_dst[w][j] = ed.x;
            s_c[w][j]   = (float)((double)__int_as_float(ed.y) * v);
        }
    }
#pragma unroll
    for (int off = 32; off > 0; off >>= 1) sum += __shfl_xor(sum, off);
    float invf = (float)(1.0 / sum);
    __builtin_amdgcn_wave_barrier();   // order LDS writes (pass A) before reads (pass B)

    float2 acc = make_float2(0.f, 0.f);
    int lim = len < CAP ? len : CAP;
    int j = 0;
    for (; j + 8 <= lim; j += 8) {
        float2 mv[8]; float c[8];
#pragma unroll
        for (int k = 0; k < 8; ++k) {
            int d = s_dst[w][j + k];
            c[k]  = s_c[w][j + k] * invf;
            mv[k] = ((const float2*)(m + (size_t)d * D_OUT))[lane];
        }
#pragma unroll
        for (int k = 0; k < 8; ++k) {
            acc.x = fmaf(c[k], mv[k].x, acc.x);
            acc.y = fmaf(c[k], mv[k].y, acc.y);
        }
    }
    for (; j < lim; ++j) {
        int d = s_dst[w][j];
        float c = s_c[w][j] * invf;
        float2 mv = ((const float2*)(m + (size_t)d * D_OUT))[lane];
        acc.x = fmaf(c, mv.x, acc.x);
        acc.y = fmaf(c, mv.y, acc.y);
    }
    for (; j < len; ++j) {   // overflow fallback (len > CAP): recompute inline
        int2 ed = edges[beg + j];
        double v = sr + dvec[ed.x];
        v = (v > 0.0) ? v : v * NEG_SLOPE;
        float c = (float)((double)__int_as_float(ed.y) * v) * invf;
        float2 mv = ((const float2*)(m + (size_t)ed.x * D_OUT))[lane];
        acc.x = fmaf(c, mv.x, acc.x);
        acc.y = fmaf(c, mv.y, acc.y);
    }
    ((float2*)(out + (size_t)r * D_OUT))[lane] = acc;
}

// ---------------------------------------------------------------------------
extern "C" void kernel_launch(void* const* d_in, const int* in_sizes, int n_in,
                              void* d_out, int out_size, void* d_ws, size_t ws_size,
                              hipStream_t stream) {
    const float* x     = (const float*)d_in[0];
    const float* W     = (const float*)d_in[1];
    const float* a     = (const float*)d_in[2];
    const float* nvals = (const float*)d_in[3];
    const int*   nsrc  = (const int*)d_in[4];
    const int*   ndst  = (const int*)d_in[5];
    const int M = in_sizes[0] / D_IN;   // 50000
    const int E = in_sizes[4];          // 1600000
    float* out = (float*)d_out;

    char* ws = (char*)d_ws;
    size_t off = 0;
    float*  m       = (float*)(ws + off);  off += (size_t)M * D_OUT * sizeof(float);  // 25.6 MB
    double* svec    = (double*)(ws + off); off += (size_t)M * sizeof(double);
    double* dvec    = (double*)(ws + off); off += (size_t)M * sizeof(double);
    int*    counts  = (int*)(ws + off);    off += ((size_t)M * sizeof(int) + 15) & ~15ull;
    int*    rowptr  = (int*)(ws + off);    off += ((size_t)(M + 1) * sizeof(int) + 15) & ~15ull;
    int*    cursor  = (int*)(ws + off);    off += ((size_t)M * sizeof(int) + 15) & ~15ull;
    int2*   edges   = (int2*)(ws + off);   off += (size_t)E * sizeof(int2);           // 12.8 MB

    hipMemsetAsync(counts, 0, (size_t)M * sizeof(int), stream);

    const int gemmBlocks  = (M + 127) / 128;     // 391
    const int countBlocks = (E + 1023) / 1024;   // 1563

    gemm_count<<<gemmBlocks + countBlocks, 256, 0, stream>>>(x, W, m, M, nsrc, counts, E, gemmBlocks);
    scan_sd<<<1 + (M + 3) / 4, 256, 0, stream>>>(counts, rowptr, cursor, m, a, svec, dvec, M);
    fill_kernel<<<countBlocks, 256, 0, stream>>>(nsrc, ndst, nvals, cursor, edges, E);
    row_kernel<<<(M + 3) / 4, 256, 0, stream>>>(rowptr, edges, svec, dvec, m, out, M);
}